// Round 6
// baseline (2029.836 us; speedup 1.0000x reference)
//
#include <hip/hip_runtime.h>

// FADE-Lite, correctness-first (round 6): fp32 inputs AND fp32 output.
// out = gate*en + (1-gate)*CARAFE(de, softmax_k(dw3x3(conv1x1(en,Wce))+up2(dw3x3(conv1x1(de,Wcd)))))
// B=4, C=256, H=64, W=64. Per-batch serialized; ws need = 3,768,320 B.

typedef unsigned short u16;
typedef unsigned int u32;

#define NB 4
#define NC 256
#define NH 64
#define NW 64
#define NH2 128
#define NW2 128

// fp32 weights in ws
#define OFF_WG   0        // 256
#define OFF_BG   256      // 1
#define OFF_WCE  272      // 6400
#define OFF_BCE  6672     // 25
#define OFF_WCD  6704     // 6400
#define OFF_WDW  13104    // 225
#define OFF_BDW  13330    // 25
#define OFF_FLAG 13356    // 1.0f = fp32 inputs, 0.0f = bf16 inputs

// per-batch fp32 buffers (reused each batch)
#define OFF_GATE 16384    // [h][w]          4096
#define OFF_DEC  20480    // [k][h][w]       102400
#define OFF_ENC  122880   // [k][y][x]       409600
#define OFF_KBF  532480   // [y][x][k]       409600   -> end 942080 floats (3.77 MB)

__device__ __forceinline__ float bf2f(u16 u){ return __uint_as_float(((u32)u) << 16); }
__device__ __forceinline__ float ldin(const void* p, int i, bool f32){
  return f32 ? ((const float*)p)[i] : bf2f(((const u16*)p)[i]);
}

// dtype detector on `de` (~N(0,1)): bf16 exp field in [0x70,0x82] (~always);
// fp32 low-mantissa halves at even u16 indices are ~uniform (~7% hit).
__global__ __launch_bounds__(256) void k_detect(const void* de_raw, float* ws){
  __shared__ int cnt;
  if (threadIdx.x == 0) cnt = 0;
  __syncthreads();
  int c = 0;
#pragma unroll
  for (int s = 0; s < 2; s++) {
    int i = (threadIdx.x + s * 256) * 2;           // even u16 idx
    u16 u = ((const u16*)de_raw)[i];
    int e = (u >> 7) & 0xff;
    if (e >= 0x70 && e <= 0x82) c++;
  }
  atomicAdd(&cnt, c);
  __syncthreads();
  if (threadIdx.x == 0) ws[OFF_FLAG] = (cnt < 256) ? 1.0f : 0.0f;
}

__global__ __launch_bounds__(256) void k_prep(const void* Wg, const void* bg,
    const void* Wce, const void* bce, const void* Wcd, const void* Wdw, const void* bdw,
    float* ws){
  bool f = ws[OFF_FLAG] != 0.f;
  int i = threadIdx.x + blockIdx.x * 256;
  if (i < 6400) {
    ws[OFF_WCE + i] = ldin(Wce, i, f);
    ws[OFF_WCD + i] = ldin(Wcd, i, f);
    if (i < 256) ws[OFF_WG + i] = ldin(Wg, i, f);
    if (i < 1)   ws[OFF_BG + i] = ldin(bg, i, f);
    if (i < 25)  ws[OFF_BCE + i] = ldin(bce, i, f);
    if (i < 225) ws[OFF_WDW + i] = ldin(Wdw, i, f);
    if (i < 25)  ws[OFF_BDW + i] = ldin(bdw, i, f);
  }
}

// gate[h][w] = sigmoid(sum_c de[b,c,h,w]*Wg[c] + bg).  <<<16,256>>>
__global__ __launch_bounds__(256) void kA_gate(const void* de, float* ws, int b){
  bool f = ws[OFF_FLAG] != 0.f;
  int idx = blockIdx.x * 256 + threadIdx.x;        // 0..4095
  int h = idx >> 6, w = idx & 63;
  float s = ws[OFF_BG];
  for (int c = 0; c < NC; c++)
    s += ldin(de, ((b * NC + c) * NH + h) * NW + w, f) * ws[OFF_WG + c];
  ws[OFF_GATE + idx] = 1.f / (1.f + __expf(-s));
}

// DEC[k][h][w] = sum_c de[b,c,h,w]*Wcd[k,c].  <<<16,256>>>
__global__ __launch_bounds__(256) void kB_dec(const void* de, float* ws, int b){
  bool f = ws[OFF_FLAG] != 0.f;
  int idx = blockIdx.x * 256 + threadIdx.x;        // (h,w)
  int h = idx >> 6, w = idx & 63;
  float acc[25];
#pragma unroll
  for (int k = 0; k < 25; k++) acc[k] = 0.f;
  for (int c = 0; c < NC; c++) {
    float v = ldin(de, ((b * NC + c) * NH + h) * NW + w, f);
#pragma unroll
    for (int k = 0; k < 25; k++) acc[k] += v * ws[OFF_WCD + k * 256 + c];
  }
#pragma unroll
  for (int k = 0; k < 25; k++)
    ws[OFF_DEC + (k * NH + h) * NW + w] = acc[k];
}

// ENC[k][y][x] = sum_c en[b,c,y,x]*Wce[k,c] + bce[k].  <<<64,256>>>
__global__ __launch_bounds__(256) void kC_enc(const void* en, float* ws, int b){
  bool f = ws[OFF_FLAG] != 0.f;
  int idx = blockIdx.x * 256 + threadIdx.x;        // (y,x)
  int y = idx >> 7, x = idx & 127;
  float acc[25];
#pragma unroll
  for (int k = 0; k < 25; k++) acc[k] = 0.f;
  for (int c = 0; c < NC; c++) {
    float v = ldin(en, ((b * NC + c) * NH2 + y) * NW2 + x, f);
#pragma unroll
    for (int k = 0; k < 25; k++) acc[k] += v * ws[OFF_WCE + k * 256 + c];
  }
#pragma unroll
  for (int k = 0; k < 25; k++)
    ws[OFF_ENC + (k * NH2 + y) * NW2 + x] = acc[k] + ws[OFF_BCE + k];
}

// raw[k] = dw3x3(ENC)[k,y,x]+bdw[k] + dw3x3(DEC)[k,h,w]+bdw[k]; KBF[y][x][k]=softmax_k(raw).
// <<<64,256>>>
__global__ __launch_bounds__(256) void kD_kern(float* ws){
  int idx = blockIdx.x * 256 + threadIdx.x;        // (y,x)
  int y = idx >> 7, x = idx & 127;
  int h = y >> 1, w = x >> 1;
  float raw[25];
#pragma unroll
  for (int k = 0; k < 25; k++) {
    float s = 2.f * ws[OFF_BDW + k];
#pragma unroll
    for (int u = 0; u < 3; u++) {
      int yy = y + u - 1, hh = h + u - 1;
#pragma unroll
      for (int v = 0; v < 3; v++) {
        int xx = x + v - 1, ww = w + v - 1;
        float wd = ws[OFF_WDW + k * 9 + u * 3 + v];
        if (yy >= 0 && yy < NH2 && xx >= 0 && xx < NW2)
          s += ws[OFF_ENC + (k * NH2 + yy) * NW2 + xx] * wd;
        if (hh >= 0 && hh < NH && ww >= 0 && ww < NW)
          s += ws[OFF_DEC + (k * NH + hh) * NW + ww] * wd;
      }
    }
    raw[k] = s;
  }
  float m = raw[0];
#pragma unroll
  for (int k = 1; k < 25; k++) m = fmaxf(m, raw[k]);
  float sum = 0.f;
#pragma unroll
  for (int k = 0; k < 25; k++) { raw[k] = __expf(raw[k] - m); sum += raw[k]; }
  float inv = 1.f / sum;
  float* dst = ws + OFF_KBF + idx * 25;
#pragma unroll
  for (int k = 0; k < 25; k++) dst[k] = raw[k] * inv;
}

// out[b,c,y,x] = g*en + (1-g)*sum_k de_pad[b,c,y/2+dy-2,x/2+dx-2]*KBF[y][x][k].  <<<16384,256>>>
// OUTPUT IS FP32 (reference returns float32).
__global__ __launch_bounds__(256) void kE_out(const void* en, const void* de,
    const float* ws, float* out, int b){
  bool f = ws[OFF_FLAG] != 0.f;
  int idx = blockIdx.x * 256 + threadIdx.x;        // (c,y,x)
  int c = idx >> 14;
  int y = (idx >> 7) & 127;
  int x = idx & 127;
  int h = y >> 1, w = x >> 1;
  const float* kb = ws + OFF_KBF + (y * NW2 + x) * 25;
  float acc = 0.f;
#pragma unroll
  for (int dy = 0; dy < 5; dy++) {
    int hh = h + dy - 2;
    if (hh < 0 || hh >= NH) continue;
#pragma unroll
    for (int dx = 0; dx < 5; dx++) {
      int ww = w + dx - 2;
      if (ww < 0 || ww >= NW) continue;
      acc += ldin(de, ((b * NC + c) * NH + hh) * NW + ww, f) * kb[dy * 5 + dx];
    }
  }
  float g = ws[OFF_GATE + h * NW + w];
  float e = ldin(en, ((b * NC + c) * NH2 + y) * NW2 + x, f);
  out[((b * NC + c) * NH2 + y) * NW2 + x] = g * e + (1.f - g) * acc;
}

// resolve input by flat element count (robust to permutation); fallback positional
static const void* find_by_size(void* const* d_in, const int* in_sizes, int n_in,
                                int want, int skip, const void* fb){
  int seen = 0;
  for (int i = 0; i < n_in; i++)
    if (in_sizes[i] == want) {
      if (seen == skip) return d_in[i];
      seen++;
    }
  return fb;
}

extern "C" void kernel_launch(void* const* d_in, const int* in_sizes, int n_in,
                              void* d_out, int out_size, void* d_ws, size_t ws_size,
                              hipStream_t stream) {
  (void)out_size; (void)ws_size;
  const void* en  = find_by_size(d_in, in_sizes, n_in, 4*256*128*128, 0, d_in[0]);
  const void* de  = find_by_size(d_in, in_sizes, n_in, 4*256*64*64,   0, d_in[1]);
  const void* Wg  = find_by_size(d_in, in_sizes, n_in, 256,           0, d_in[2]);
  const void* bg  = find_by_size(d_in, in_sizes, n_in, 1,             0, d_in[3]);
  const void* Wce = find_by_size(d_in, in_sizes, n_in, 6400,          0, d_in[4]);
  const void* bce = find_by_size(d_in, in_sizes, n_in, 25,            0, d_in[5]);
  const void* Wcd = find_by_size(d_in, in_sizes, n_in, 6400,          1, d_in[6]);
  const void* Wdw = find_by_size(d_in, in_sizes, n_in, 225,           0, d_in[7]);
  const void* bdw = find_by_size(d_in, in_sizes, n_in, 25,            1, d_in[8]);
  float* ws = (float*)d_ws;
  float* out = (float*)d_out;

  hipLaunchKernelGGL(k_detect, dim3(1), dim3(256), 0, stream, de, ws);
  hipLaunchKernelGGL(k_prep, dim3(25), dim3(256), 0, stream,
                     Wg, bg, Wce, bce, Wcd, Wdw, bdw, ws);

  for (int b = 0; b < NB; b++) {
    hipLaunchKernelGGL(kA_gate, dim3(16),    dim3(256), 0, stream, de, ws, b);
    hipLaunchKernelGGL(kB_dec,  dim3(16),    dim3(256), 0, stream, de, ws, b);
    hipLaunchKernelGGL(kC_enc,  dim3(64),    dim3(256), 0, stream, en, ws, b);
    hipLaunchKernelGGL(kD_kern, dim3(64),    dim3(256), 0, stream, ws);
    hipLaunchKernelGGL(kE_out,  dim3(16384), dim3(256), 0, stream, en, de, ws, out, b);
  }
}

// Round 7
// 382.825 us; speedup vs baseline: 5.3023x; 5.3023x over previous
//
#include <hip/hip_runtime.h>

// FADE-Lite round 7: reinstate the optimized batched pipeline (round-3 compute,
// proven correct by absmax-artifact identity with the verified naive version),
// with fp32 output. Naive per-batch path kept as ws_size fallback.
//
// out = gate*en + (1-gate)*CARAFE(de, softmax_k(dw3x3(conv1x1(en,Wce))+up2(dw3x3(conv1x1(de,Wcd)))))
// B=4, C=256, H=64, W=64. Inputs fp32 (runtime-detected), output fp32.

typedef unsigned short u16;
typedef unsigned int u32;

#define NB 4
#define NC 256
#define NH 64
#define NW 64
#define NH2 128
#define NW2 128

// fp32 weights in ws (shared by both paths)
#define OFF_WG   0
#define OFF_BG   256
#define OFF_WCE  272
#define OFF_BCE  6672
#define OFF_WCD  6704
#define OFF_WDW  13104
#define OFF_BDW  13330
#define OFF_FLAG 13356    // 1.0f = fp32 inputs, 0.0f = bf16 inputs

// ---- optimized (full-batch) layout, floats ----
#define OFF_GATE 16384    // 4*4096 fp32                    -> 32768
#define OFF_KB   32768    // 4*4096*100 u16 (819200 fl)     -> 851968
#define OFF_ENC  851968   // 4*25*16384 fp32                -> 2490368
#define OFF_DEC  2490368  // 4*25*4096 fp32                 -> 2899968
#define OFF_DET  851968   // 4*68*68*256 u16, aliases dead ENC+DEC after o4 -> 3219456
#define FULL_NEED_BYTES 12877824ull

// ---- naive (per-batch) layout, floats ----
#define NGATE 16384
#define NDEC  20480
#define NENC  122880
#define NKBF  532480      // -> end 942080 (3.77 MB)

__device__ __forceinline__ float bf2f(u16 u){ return __uint_as_float(((u32)u) << 16); }
__device__ __forceinline__ u16 f2bf(float f){
  u32 x = __float_as_uint(f);
  return (u16)((x + 0x7fffu + ((x >> 16) & 1u)) >> 16);  // RNE (finite)
}
__device__ __forceinline__ float ldin(const void* p, int i, bool f32){
  return f32 ? ((const float*)p)[i] : bf2f(((const u16*)p)[i]);
}

// dtype detector on `de` (~N(0,1)): bf16 exp in [0x70,0x82] nearly always;
// fp32 low-mantissa u16s ~uniform (~7% hit).
__global__ __launch_bounds__(256) void k_detect(const void* de_raw, float* ws){
  __shared__ int cnt;
  if (threadIdx.x == 0) cnt = 0;
  __syncthreads();
  int c = 0;
#pragma unroll
  for (int s = 0; s < 2; s++) {
    int i = (threadIdx.x + s * 256) * 2;
    u16 u = ((const u16*)de_raw)[i];
    int e = (u >> 7) & 0xff;
    if (e >= 0x70 && e <= 0x82) c++;
  }
  atomicAdd(&cnt, c);
  __syncthreads();
  if (threadIdx.x == 0) ws[OFF_FLAG] = (cnt < 256) ? 1.0f : 0.0f;
}

__global__ __launch_bounds__(256) void k_prep(const void* Wg, const void* bg,
    const void* Wce, const void* bce, const void* Wcd, const void* Wdw, const void* bdw,
    float* ws){
  bool f = ws[OFF_FLAG] != 0.f;
  int i = threadIdx.x + blockIdx.x * 256;
  if (i < 6400) {
    ws[OFF_WCE + i] = ldin(Wce, i, f);
    ws[OFF_WCD + i] = ldin(Wcd, i, f);
    if (i < 256) ws[OFF_WG + i] = ldin(Wg, i, f);
    if (i < 1)   ws[OFF_BG + i] = ldin(bg, i, f);
    if (i < 25)  ws[OFF_BCE + i] = ldin(bce, i, f);
    if (i < 225) ws[OFF_WDW + i] = ldin(Wdw, i, f);
    if (i < 25)  ws[OFF_BDW + i] = ldin(bdw, i, f);
  }
}

// ================= optimized path =================

// DEC = conv1x1(de, W_cd); GATE = sigmoid(conv1x1(de,W_gate)+b_gate)
// grid = B*H (256), block 256 = 4 c-groups x 64 w
__global__ __launch_bounds__(256) void o1_dec_gate(const void* de, float* ws){
  __shared__ float red[4][26][64];
  bool f = ws[OFF_FLAG] != 0.f;
  int b = blockIdx.x >> 6;
  int h = blockIdx.x & 63;
  int g = threadIdx.x >> 6;
  int w = threadIdx.x & 63;
  int c0 = __builtin_amdgcn_readfirstlane(g * 64);
  float acc[26];
#pragma unroll
  for (int o = 0; o < 26; o++) acc[o] = 0.f;
  int idx = ((b * NC + c0) * NH + h) * NW + w;
  for (int ci = 0; ci < 64; ci++) {
    float v = ldin(de, idx, f); idx += NH * NW;
    int c = c0 + ci;
    acc[25] += ws[OFF_WG + c] * v;
#pragma unroll
    for (int k = 0; k < 25; k++) acc[k] += ws[OFF_WCD + k * 256 + c] * v;
  }
#pragma unroll
  for (int o = 0; o < 26; o++) red[g][o][w] = acc[o];
  __syncthreads();
  for (int item = threadIdx.x; item < 26 * 64; item += 256) {
    int o = item >> 6; int ww = item & 63;
    float s = red[0][o][ww] + red[1][o][ww] + red[2][o][ww] + red[3][o][ww];
    if (o < 25) ws[OFF_DEC + ((b * 25 + o) * NH + h) * NW + ww] = s;
    else {
      float z = s + ws[OFF_BG];
      ws[OFF_GATE + (b * NH + h) * NW + ww] = 1.f / (1.f + __expf(-z));
    }
  }
}

// DET[b][p][q][c] = de[b][c][p-2][q-2] (0 outside), bf16. Runs AFTER o4 (aliases ENC+DEC).
// grid = B*68, block 256 (=c)
__global__ __launch_bounds__(256) void o2_det(const void* de, float* ws){
  bool f = ws[OFF_FLAG] != 0.f;
  u16* det = (u16*)(ws + OFF_DET);
  int b = blockIdx.x / 68;
  int p = blockIdx.x % 68;
  int c = threadIdx.x;
  int h = p - 2;
  bool hv = (h >= 0 && h < NH);
  int sbase = ((b * NC + c) * NH + (hv ? h : 0)) * NW;
  u16* dst = det + ((b * 68 + p) * 68) * NC + c;
  for (int q = 0; q < 68; q++) {
    int w = q - 2;
    float v = (hv && w >= 0 && w < NW) ? ldin(de, sbase + w, f) : 0.f;
    dst[q * NC] = f2bf(v);
  }
}

// ENC = conv1x1(en, W_ce)+b_ce.  grid = B*128 (512), block 256 = 2 c-groups x 128 x
__global__ __launch_bounds__(256) void o3_enc(const void* en, float* ws){
  __shared__ float red[2][25][128];
  bool f = ws[OFF_FLAG] != 0.f;
  int b = blockIdx.x >> 7;
  int y = blockIdx.x & 127;
  int g = threadIdx.x >> 7;
  int x = threadIdx.x & 127;
  int c0 = __builtin_amdgcn_readfirstlane(g * 128);
  float acc[25];
#pragma unroll
  for (int k = 0; k < 25; k++) acc[k] = 0.f;
  int idx = ((b * NC + c0) * NH2 + y) * NW2 + x;
  for (int ci = 0; ci < 128; ci++) {
    float v = ldin(en, idx, f); idx += NH2 * NW2;
    int c = c0 + ci;
#pragma unroll
    for (int k = 0; k < 25; k++) acc[k] += ws[OFF_WCE + k * 256 + c] * v;
  }
#pragma unroll
  for (int k = 0; k < 25; k++) red[g][k][x] = acc[k];
  __syncthreads();
  for (int item = threadIdx.x; item < 25 * 128; item += 256) {
    int k = item >> 7; int xx = item & 127;
    float s = red[0][k][xx] + red[1][k][xx] + ws[OFF_BCE + k];
    ws[OFF_ENC + ((b * 25 + k) * NH2 + y) * NW2 + xx] = s;
  }
}

// raw = dw3x3(ENC)+b + up2(dw3x3(DEC)+b); softmax over 25 -> KB bf16 [b][h][w][tap*4+st]
// grid = B*64 (256), block 256 = 2 rows x 128 x
__global__ __launch_bounds__(256) void o4_kernels(float* ws){
  int b = blockIdx.x >> 6;
  int y = ((blockIdx.x & 63) << 1) + (threadIdx.x >> 7);
  int x = threadIdx.x & 127;
  int h = y >> 1, w = x >> 1;
  const float* enc = ws + OFF_ENC + (b * 25) * NH2 * NW2;
  const float* dec = ws + OFF_DEC + (b * 25) * NH * NW;
  float raw[25];
#pragma unroll
  for (int k = 0; k < 25; k++) {
    float s = 2.f * ws[OFF_BDW + k];
#pragma unroll
    for (int u = 0; u < 3; u++) {
      int yy = y + u - 1, hh = h + u - 1;
#pragma unroll
      for (int v = 0; v < 3; v++) {
        int xx = x + v - 1, w2 = w + v - 1;
        float wd = ws[OFF_WDW + k * 9 + u * 3 + v];
        if (yy >= 0 && yy < NH2 && xx >= 0 && xx < NW2)
          s += enc[(k * NH2 + yy) * NW2 + xx] * wd;
        if (hh >= 0 && hh < NH && w2 >= 0 && w2 < NW)
          s += dec[(k * NH + hh) * NW + w2] * wd;
      }
    }
    raw[k] = s;
  }
  float m = raw[0];
#pragma unroll
  for (int k = 1; k < 25; k++) m = fmaxf(m, raw[k]);
  float sum = 0.f;
#pragma unroll
  for (int k = 0; k < 25; k++) { raw[k] = __expf(raw[k] - m); sum += raw[k]; }
  float inv = 1.f / sum;
  int st = ((y & 1) << 1) + (x & 1);
  u16* kbu = (u16*)(ws + OFF_KB);
  u16* dst = kbu + ((b * NH + h) * NW + w) * 100 + st;
#pragma unroll
  for (int k = 0; k < 25; k++) dst[k * 4] = f2bf(raw[k] * inv);
}

// Channel-major carafe + gate blend, fp32 out. grid = B*64*4 (1024), block 256 (4 waves).
__global__ __launch_bounds__(256) void o5_final(const void* en, float* ws, float* out){
  __shared__ u16 stag[2][32][260];
  bool f = ws[OFF_FLAG] != 0.f;
  const u16* det = (const u16*)(ws + OFF_DET);
  const u16* kbu = (const u16*)(ws + OFF_KB);
  const float* gate = ws + OFF_GATE;

  int b = blockIdx.x >> 8;
  int rem = blockIdx.x & 255;
  int h = rem >> 2;
  int w0b = (rem & 3) * 16;
  int wave = threadIdx.x >> 6;
  int lane = threadIdx.x & 63;
  int c4 = lane * 4;

  for (int i = 0; i < 4; i++) {
    int wu = __builtin_amdgcn_readfirstlane(w0b + wave * 4 + i);
    const u16* kp = kbu + ((b * NH + h) * NW + wu) * 100;
    float acc[4][4];
#pragma unroll
    for (int st = 0; st < 4; st++)
#pragma unroll
      for (int j = 0; j < 4; j++) acc[st][j] = 0.f;

#pragma unroll
    for (int dy = 0; dy < 5; dy++) {
      const u16* dp = det + (((b * 68 + h + dy) * 68 + wu) * NC) + c4;
#pragma unroll
      for (int dx = 0; dx < 5; dx++) {
        ushort4 uv = *(const ushort4*)(dp + dx * NC);
        float v0 = bf2f(uv.x), v1 = bf2f(uv.y), v2 = bf2f(uv.z), v3 = bf2f(uv.w);
        const u32* kpu = (const u32*)(kp + (dy * 5 + dx) * 4);
        u32 k01 = kpu[0], k23 = kpu[1];
        float k0 = bf2f((u16)(k01 & 0xffffu));
        float k1 = bf2f((u16)(k01 >> 16));
        float k2 = bf2f((u16)(k23 & 0xffffu));
        float k3 = bf2f((u16)(k23 >> 16));
        acc[0][0] += k0 * v0; acc[0][1] += k0 * v1; acc[0][2] += k0 * v2; acc[0][3] += k0 * v3;
        acc[1][0] += k1 * v0; acc[1][1] += k1 * v1; acc[1][2] += k1 * v2; acc[1][3] += k1 * v3;
        acc[2][0] += k2 * v0; acc[2][1] += k2 * v1; acc[2][2] += k2 * v2; acc[2][3] += k2 * v3;
        acc[3][0] += k3 * v0; acc[3][1] += k3 * v1; acc[3][2] += k3 * v2; acc[3][3] += k3 * v3;
      }
    }
    int xl = (wave * 4 + i) * 2;
#pragma unroll
    for (int s = 0; s < 2; s++)
#pragma unroll
      for (int t = 0; t < 2; t++) {
        int st = s * 2 + t;
        ushort4 pv;
        pv.x = f2bf(acc[st][0]); pv.y = f2bf(acc[st][1]);
        pv.z = f2bf(acc[st][2]); pv.w = f2bf(acc[st][3]);
        *(ushort4*)&stag[s][xl + t][c4] = pv;
      }
  }
  __syncthreads();

  int xp = threadIdx.x & 31;
  int cb = (threadIdx.x >> 5) * 2;
  int x = w0b * 2 + xp;
  int wpix = w0b + (xp >> 1);
  float g = gate[(b * NH + h) * NW + wpix];
  float gi = 1.f - g;
#pragma unroll
  for (int pass = 0; pass < 16; pass++) {
    int c = cb + pass * 16;
#pragma unroll
    for (int s = 0; s < 2; s++) {
      int y = 2 * h + s;
      u32 rr = *(const u32*)&stag[s][xp][c];
      float cr0 = bf2f((u16)(rr & 0xffffu));
      float cr1 = bf2f((u16)(rr >> 16));
      int eidx = ((b * NC + c) * NH2 + y) * NW2 + x;
      float e0 = ldin(en, eidx, f);
      float e1 = ldin(en, eidx + NH2 * NW2, f);
      out[eidx] = g * e0 + gi * cr0;
      out[eidx + NH2 * NW2] = g * e1 + gi * cr1;
    }
  }
}

// ================= naive fallback path (verified round 6) =================

__global__ __launch_bounds__(256) void kA_gate(const void* de, float* ws, int b){
  bool f = ws[OFF_FLAG] != 0.f;
  int idx = blockIdx.x * 256 + threadIdx.x;
  int h = idx >> 6, w = idx & 63;
  float s = ws[OFF_BG];
  for (int c = 0; c < NC; c++)
    s += ldin(de, ((b * NC + c) * NH + h) * NW + w, f) * ws[OFF_WG + c];
  ws[NGATE + idx] = 1.f / (1.f + __expf(-s));
}

__global__ __launch_bounds__(256) void kB_dec(const void* de, float* ws, int b){
  bool f = ws[OFF_FLAG] != 0.f;
  int idx = blockIdx.x * 256 + threadIdx.x;
  int h = idx >> 6, w = idx & 63;
  float acc[25];
#pragma unroll
  for (int k = 0; k < 25; k++) acc[k] = 0.f;
  for (int c = 0; c < NC; c++) {
    float v = ldin(de, ((b * NC + c) * NH + h) * NW + w, f);
#pragma unroll
    for (int k = 0; k < 25; k++) acc[k] += v * ws[OFF_WCD + k * 256 + c];
  }
#pragma unroll
  for (int k = 0; k < 25; k++)
    ws[NDEC + (k * NH + h) * NW + w] = acc[k];
}

__global__ __launch_bounds__(256) void kC_enc(const void* en, float* ws, int b){
  bool f = ws[OFF_FLAG] != 0.f;
  int idx = blockIdx.x * 256 + threadIdx.x;
  int y = idx >> 7, x = idx & 127;
  float acc[25];
#pragma unroll
  for (int k = 0; k < 25; k++) acc[k] = 0.f;
  for (int c = 0; c < NC; c++) {
    float v = ldin(en, ((b * NC + c) * NH2 + y) * NW2 + x, f);
#pragma unroll
    for (int k = 0; k < 25; k++) acc[k] += v * ws[OFF_WCE + k * 256 + c];
  }
#pragma unroll
  for (int k = 0; k < 25; k++)
    ws[NENC + (k * NH2 + y) * NW2 + x] = acc[k] + ws[OFF_BCE + k];
}

__global__ __launch_bounds__(256) void kD_kern(float* ws){
  int idx = blockIdx.x * 256 + threadIdx.x;
  int y = idx >> 7, x = idx & 127;
  int h = y >> 1, w = x >> 1;
  float raw[25];
#pragma unroll
  for (int k = 0; k < 25; k++) {
    float s = 2.f * ws[OFF_BDW + k];
#pragma unroll
    for (int u = 0; u < 3; u++) {
      int yy = y + u - 1, hh = h + u - 1;
#pragma unroll
      for (int v = 0; v < 3; v++) {
        int xx = x + v - 1, ww = w + v - 1;
        float wd = ws[OFF_WDW + k * 9 + u * 3 + v];
        if (yy >= 0 && yy < NH2 && xx >= 0 && xx < NW2)
          s += ws[NENC + (k * NH2 + yy) * NW2 + xx] * wd;
        if (hh >= 0 && hh < NH && ww >= 0 && ww < NW)
          s += ws[NDEC + (k * NH + hh) * NW + ww] * wd;
      }
    }
    raw[k] = s;
  }
  float m = raw[0];
#pragma unroll
  for (int k = 1; k < 25; k++) m = fmaxf(m, raw[k]);
  float sum = 0.f;
#pragma unroll
  for (int k = 0; k < 25; k++) { raw[k] = __expf(raw[k] - m); sum += raw[k]; }
  float inv = 1.f / sum;
  float* dst = ws + NKBF + idx * 25;
#pragma unroll
  for (int k = 0; k < 25; k++) dst[k] = raw[k] * inv;
}

__global__ __launch_bounds__(256) void kE_out(const void* en, const void* de,
    const float* ws, float* out, int b){
  bool f = ws[OFF_FLAG] != 0.f;
  int idx = blockIdx.x * 256 + threadIdx.x;
  int c = idx >> 14;
  int y = (idx >> 7) & 127;
  int x = idx & 127;
  int h = y >> 1, w = x >> 1;
  const float* kb = ws + NKBF + (y * NW2 + x) * 25;
  float acc = 0.f;
#pragma unroll
  for (int dy = 0; dy < 5; dy++) {
    int hh = h + dy - 2;
    if (hh < 0 || hh >= NH) continue;
#pragma unroll
    for (int dx = 0; dx < 5; dx++) {
      int ww = w + dx - 2;
      if (ww < 0 || ww >= NW) continue;
      acc += ldin(de, ((b * NC + c) * NH + hh) * NW + ww, f) * kb[dy * 5 + dx];
    }
  }
  float g = ws[NGATE + h * NW + w];
  float e = ldin(en, ((b * NC + c) * NH2 + y) * NW2 + x, f);
  out[((b * NC + c) * NH2 + y) * NW2 + x] = g * e + (1.f - g) * acc;
}

// resolve input by flat element count (robust to permutation); fallback positional
static const void* find_by_size(void* const* d_in, const int* in_sizes, int n_in,
                                int want, int skip, const void* fb){
  int seen = 0;
  for (int i = 0; i < n_in; i++)
    if (in_sizes[i] == want) {
      if (seen == skip) return d_in[i];
      seen++;
    }
  return fb;
}

extern "C" void kernel_launch(void* const* d_in, const int* in_sizes, int n_in,
                              void* d_out, int out_size, void* d_ws, size_t ws_size,
                              hipStream_t stream) {
  (void)out_size;
  const void* en  = find_by_size(d_in, in_sizes, n_in, 4*256*128*128, 0, d_in[0]);
  const void* de  = find_by_size(d_in, in_sizes, n_in, 4*256*64*64,   0, d_in[1]);
  const void* Wg  = find_by_size(d_in, in_sizes, n_in, 256,           0, d_in[2]);
  const void* bg  = find_by_size(d_in, in_sizes, n_in, 1,             0, d_in[3]);
  const void* Wce = find_by_size(d_in, in_sizes, n_in, 6400,          0, d_in[4]);
  const void* bce = find_by_size(d_in, in_sizes, n_in, 25,            0, d_in[5]);
  const void* Wcd = find_by_size(d_in, in_sizes, n_in, 6400,          1, d_in[6]);
  const void* Wdw = find_by_size(d_in, in_sizes, n_in, 225,           0, d_in[7]);
  const void* bdw = find_by_size(d_in, in_sizes, n_in, 25,            1, d_in[8]);
  float* ws = (float*)d_ws;
  float* out = (float*)d_out;

  hipLaunchKernelGGL(k_detect, dim3(1), dim3(256), 0, stream, de, ws);
  hipLaunchKernelGGL(k_prep, dim3(25), dim3(256), 0, stream,
                     Wg, bg, Wce, bce, Wcd, Wdw, bdw, ws);

  if (ws_size >= FULL_NEED_BYTES) {
    hipLaunchKernelGGL(o1_dec_gate, dim3(NB * NH),     dim3(256), 0, stream, de, ws);
    hipLaunchKernelGGL(o3_enc,      dim3(NB * NH2),    dim3(256), 0, stream, en, ws);
    hipLaunchKernelGGL(o4_kernels,  dim3(NB * NH),     dim3(256), 0, stream, ws);
    hipLaunchKernelGGL(o2_det,      dim3(NB * 68),     dim3(256), 0, stream, de, ws);
    hipLaunchKernelGGL(o5_final,    dim3(NB * NH * 4), dim3(256), 0, stream, en, ws, out);
  } else {
    for (int b = 0; b < NB; b++) {
      hipLaunchKernelGGL(kA_gate, dim3(16),    dim3(256), 0, stream, de, ws, b);
      hipLaunchKernelGGL(kB_dec,  dim3(16),    dim3(256), 0, stream, de, ws, b);
      hipLaunchKernelGGL(kC_enc,  dim3(64),    dim3(256), 0, stream, en, ws, b);
      hipLaunchKernelGGL(kD_kern, dim3(64),    dim3(256), 0, stream, ws);
      hipLaunchKernelGGL(kE_out,  dim3(16384), dim3(256), 0, stream, en, de, ws, out, b);
    }
  }
}